// Round 1
// baseline (860.851 us; speedup 1.0000x reference)
//
#include <hip/hip_runtime.h>
#include <hip/hip_bf16.h>
#include <stdint.h>

typedef __attribute__((ext_vector_type(8))) short short8;
typedef __attribute__((ext_vector_type(4))) float f32x4;

#define AS1 __attribute__((address_space(1)))
#define AS3 __attribute__((address_space(3)))

// RNE float->bf16 (inputs are finite; no NaN handling needed)
static __device__ __forceinline__ unsigned short f2bf(float f) {
    unsigned int u = __float_as_uint(f);
    u += 0x7FFFu + ((u >> 16) & 1u);
    return (unsigned short)(u >> 16);
}

__global__ void init_amax(unsigned int* amax) {
    if (threadIdx.x < 2) amax[threadIdx.x] = 0u;
}

__global__ void absmax_kernel(const float4* __restrict__ w, size_t n4,
                              unsigned int* __restrict__ out) {
    float m = 0.0f;
    size_t i = (size_t)blockIdx.x * blockDim.x + threadIdx.x;
    size_t stride = (size_t)gridDim.x * blockDim.x;
    for (; i < n4; i += stride) {
        float4 v = w[i];
        m = fmaxf(m, fmaxf(fmaxf(fabsf(v.x), fabsf(v.y)),
                           fmaxf(fabsf(v.z), fabsf(v.w))));
    }
    #pragma unroll
    for (int off = 32; off > 0; off >>= 1)
        m = fmaxf(m, __shfl_down(m, off, 64));
    __shared__ float sm[4];
    int lane = threadIdx.x & 63, wid = threadIdx.x >> 6;
    if (lane == 0) sm[wid] = m;
    __syncthreads();
    if (threadIdx.x == 0) {
        float bm = fmaxf(fmaxf(sm[0], sm[1]), fmaxf(sm[2], sm[3]));
        atomicMax(out, __float_as_uint(bm));  // floats >=0: uint bit-compare is monotone
    }
}

// FP4 E2M1 quantize to exact bf16 grid value (scale kept separate).
// idx = sum(a > mids[j]) matches np.searchsorted(mids, a, side='left').
static __device__ __forceinline__ unsigned short quant_one(float wv, float scale) {
    float a = fabsf(wv) / scale;                  // exact IEEE div, matches reference
    int idx = (a > 0.25f) + (a > 0.75f) + (a > 1.25f) + (a > 1.75f)
            + (a > 2.5f)  + (a > 3.5f)  + (a > 5.0f);
    // bf16 bit patterns of {0,0.5,1,1.5} and {2,3,4,6}, packed (no scratch array)
    const unsigned long long lo = 0x3FC03F803F000000ull;
    const unsigned long long hi = 0x40C0408040404000ull;
    unsigned long long tab = (idx < 4) ? lo : hi;
    unsigned short mag = (unsigned short)(tab >> ((idx & 3) * 16));
    unsigned short sgn = (unsigned short)((__float_as_uint(wv) >> 16) & 0x8000u);
    return (unsigned short)(mag | sgn);
}

__global__ void quant_kernel(const float4* __restrict__ w, size_t n4,
                             const unsigned int* __restrict__ amax,
                             ushort4* __restrict__ q) {
    const float scale = __uint_as_float(*amax) / 6.0f;
    size_t i = (size_t)blockIdx.x * blockDim.x + threadIdx.x;
    size_t stride = (size_t)gridDim.x * blockDim.x;
    for (; i < n4; i += stride) {
        float4 v = w[i];
        ushort4 o;
        o.x = quant_one(v.x, scale);
        o.y = quant_one(v.y, scale);
        o.z = quant_one(v.z, scale);
        o.w = quant_one(v.w, scale);
        q[i] = o;
    }
}

__global__ void cast_bf16_kernel(const float4* __restrict__ x, size_t n4,
                                 ushort4* __restrict__ o) {
    size_t i = (size_t)blockIdx.x * blockDim.x + threadIdx.x;
    size_t stride = (size_t)gridDim.x * blockDim.x;
    for (; i < n4; i += stride) {
        float4 v = x[i];
        ushort4 r;
        r.x = f2bf(v.x); r.y = f2bf(v.y); r.z = f2bf(v.z); r.w = f2bf(v.w);
        o[i] = r;
    }
}

// C[M][N] = A[M][K] (bf16) * B[N][K]^T (bf16), f32 accumulate.
// m97 structure: 128x128 tile, BK=32, 4 waves each 64x64, global_load_lds w=16.
// Epilogue: RELU_BF16 ? h=relu(acc*scale+bias) as bf16 : y=acc*scale+bias as f32.
template <int RELU_BF16>
__global__ __launch_bounds__(256)
void gemm_bt(const unsigned short* __restrict__ A,
             const unsigned short* __restrict__ B,
             const float* __restrict__ bias,
             const unsigned int* __restrict__ amax,
             float* __restrict__ outF,
             unsigned short* __restrict__ outH,
             int M, int N, int K) {
    __shared__ unsigned short sA[128 * 32];
    __shared__ unsigned short sB[128 * 32];

    const int tid  = threadIdx.x;
    const int lane = tid & 63;
    const int wid  = tid >> 6;
    const int wr   = wid >> 1;       // wave row (2x2 wave grid, 64x64 each)
    const int wc   = wid & 1;
    const int col0 = blockIdx.x * 128;
    const int row0 = blockIdx.y * 128;

    f32x4 acc[4][4] = {};

    // staging map: thread t covers 8 bf16 (16B); row = t/4, kcol = (t%4)*8
    const int sr = tid >> 2;
    const int sc = (tid & 3) * 8;
    const unsigned short* gA0 = A + (size_t)(row0 + sr) * K + sc;
    const unsigned short* gA1 = A + (size_t)(row0 + 64 + sr) * K + sc;
    const unsigned short* gB0 = B + (size_t)(col0 + sr) * K + sc;
    const unsigned short* gB1 = B + (size_t)(col0 + 64 + sr) * K + sc;

    for (int kt = 0; kt < K; kt += 32) {
        __builtin_amdgcn_global_load_lds((const AS1 unsigned int*)(gA0 + kt),
                                         (AS3 unsigned int*)(sA + tid * 8), 16, 0, 0);
        __builtin_amdgcn_global_load_lds((const AS1 unsigned int*)(gA1 + kt),
                                         (AS3 unsigned int*)(sA + 2048 + tid * 8), 16, 0, 0);
        __builtin_amdgcn_global_load_lds((const AS1 unsigned int*)(gB0 + kt),
                                         (AS3 unsigned int*)(sB + tid * 8), 16, 0, 0);
        __builtin_amdgcn_global_load_lds((const AS1 unsigned int*)(gB1 + kt),
                                         (AS3 unsigned int*)(sB + 2048 + tid * 8), 16, 0, 0);
        __syncthreads();  // compiler emits s_waitcnt vmcnt(0) before s_barrier

        // fragment loads: A row = lane&15, k = (lane>>4)*8.. ; B col likewise
        const unsigned short* pa = sA + (wr * 64 + (lane & 15)) * 32 + (lane >> 4) * 8;
        const unsigned short* pb = sB + (wc * 64 + (lane & 15)) * 32 + (lane >> 4) * 8;
        short8 av[4], bv[4];
        #pragma unroll
        for (int i = 0; i < 4; ++i) {
            av[i] = *(const short8*)(pa + i * 16 * 32);
            bv[i] = *(const short8*)(pb + i * 16 * 32);
        }
        #pragma unroll
        for (int i = 0; i < 4; ++i)
            #pragma unroll
            for (int j = 0; j < 4; ++j)
                acc[i][j] = __builtin_amdgcn_mfma_f32_16x16x32_bf16(av[i], bv[j],
                                                                   acc[i][j], 0, 0, 0);
        __syncthreads();
    }

    // epilogue: C/D layout (verified m89/m91): col = lane&15, row = (lane>>4)*4 + r
    const float scale = __uint_as_float(*amax) / 6.0f;
    #pragma unroll
    for (int j = 0; j < 4; ++j) {
        const int col = col0 + wc * 64 + j * 16 + (lane & 15);
        const float bvv = bias[col];
        #pragma unroll
        for (int i = 0; i < 4; ++i) {
            const int rbase = row0 + wr * 64 + i * 16 + (lane >> 4) * 4;
            #pragma unroll
            for (int r = 0; r < 4; ++r) {
                float v = acc[i][j][r] * scale + bvv;
                if (RELU_BF16) {
                    v = fmaxf(v, 0.0f);
                    outH[(size_t)(rbase + r) * N + col] = f2bf(v);
                } else {
                    outF[(size_t)(rbase + r) * N + col] = v;
                }
            }
        }
    }
}

extern "C" void kernel_launch(void* const* d_in, const int* in_sizes, int n_in,
                              void* d_out, int out_size, void* d_ws, size_t ws_size,
                              hipStream_t stream) {
    const float* x  = (const float*)d_in[0];   // [8192, 2048]
    const float* W1 = (const float*)d_in[1];   // [8192, 2048]
    const float* b1 = (const float*)d_in[2];   // [8192]
    const float* W2 = (const float*)d_in[3];   // [2048, 8192]
    const float* b2 = (const float*)d_in[4];   // [2048]
    float* out = (float*)d_out;                // [8192, 2048] f32

    const int Bm = 8192, Din = 2048, Dh = 8192, Dout = 2048;
    const size_t nW1 = (size_t)Dh * Din;
    const size_t nW2 = (size_t)Dout * Dh;
    const size_t nX  = (size_t)Bm * Din;
    const size_t nH  = (size_t)Bm * Dh;

    // ws layout: [amax x2 | pad to 256B | Q1 bf16 | Q2 bf16 | Xb bf16 | H bf16]
    const size_t need = 256 + 2 * (nW1 + nW2 + nX + nH);
    if (ws_size < need) return;  // insufficient scratch; fail loudly via validation

    uint8_t* ws = (uint8_t*)d_ws;
    unsigned int*   amax = (unsigned int*)ws;
    unsigned short* Q1 = (unsigned short*)(ws + 256);
    unsigned short* Q2 = Q1 + nW1;
    unsigned short* Xb = Q2 + nW2;
    unsigned short* H  = Xb + nX;

    init_amax<<<1, 64, 0, stream>>>(amax);
    absmax_kernel<<<1024, 256, 0, stream>>>((const float4*)W1, nW1 / 4, amax + 0);
    absmax_kernel<<<1024, 256, 0, stream>>>((const float4*)W2, nW2 / 4, amax + 1);
    quant_kernel<<<2048, 256, 0, stream>>>((const float4*)W1, nW1 / 4, amax + 0, (ushort4*)Q1);
    quant_kernel<<<2048, 256, 0, stream>>>((const float4*)W2, nW2 / 4, amax + 1, (ushort4*)Q2);
    cast_bf16_kernel<<<2048, 256, 0, stream>>>((const float4*)x, nX / 4, (ushort4*)Xb);

    // h = relu(scale1 * (x @ Q1^T) + b1)  -> bf16
    gemm_bt<1><<<dim3(Dh / 128, Bm / 128), 256, 0, stream>>>(Xb, Q1, b1, amax + 0,
                                                             nullptr, H, Bm, Dh, Din);
    // y = scale2 * (h @ Q2^T) + b2 -> f32
    gemm_bt<0><<<dim3(Dout / 128, Bm / 128), 256, 0, stream>>>(H, Q2, b2, amax + 1,
                                                               out, nullptr, Bm, Dout, Dh);
}

// Round 2
// 582.946 us; speedup vs baseline: 1.4767x; 1.4767x over previous
//
#include <hip/hip_runtime.h>
#include <hip/hip_bf16.h>
#include <stdint.h>

typedef __attribute__((ext_vector_type(8))) short short8;
typedef __attribute__((ext_vector_type(4))) float f32x4;

#define AS1 __attribute__((address_space(1)))
#define AS3 __attribute__((address_space(3)))

// RNE float->bf16 (inputs are finite; no NaN handling needed)
static __device__ __forceinline__ unsigned short f2bf(float f) {
    unsigned int u = __float_as_uint(f);
    u += 0x7FFFu + ((u >> 16) & 1u);
    return (unsigned short)(u >> 16);
}

__global__ void init_amax(unsigned int* amax) {
    if (threadIdx.x < 2) amax[threadIdx.x] = 0u;
}

__global__ void absmax_kernel(const float4* __restrict__ w, size_t n4,
                              unsigned int* __restrict__ out) {
    float m = 0.0f;
    size_t i = (size_t)blockIdx.x * blockDim.x + threadIdx.x;
    size_t stride = (size_t)gridDim.x * blockDim.x;
    for (; i < n4; i += stride) {
        float4 v = w[i];
        m = fmaxf(m, fmaxf(fmaxf(fabsf(v.x), fabsf(v.y)),
                           fmaxf(fabsf(v.z), fabsf(v.w))));
    }
    #pragma unroll
    for (int off = 32; off > 0; off >>= 1)
        m = fmaxf(m, __shfl_down(m, off, 64));
    __shared__ float sm[4];
    int lane = threadIdx.x & 63, wid = threadIdx.x >> 6;
    if (lane == 0) sm[wid] = m;
    __syncthreads();
    if (threadIdx.x == 0) {
        float bm = fmaxf(fmaxf(sm[0], sm[1]), fmaxf(sm[2], sm[3]));
        atomicMax(out, __float_as_uint(bm));  // floats >=0: uint bit-compare is monotone
    }
}

// FP4 E2M1 quantize to exact bf16 grid value (scale kept separate).
// idx = sum(a > mids[j]) matches np.searchsorted(mids, a, side='left').
static __device__ __forceinline__ unsigned short quant_one(float wv, float scale) {
    float a = fabsf(wv) / scale;                  // exact IEEE div, matches reference
    int idx = (a > 0.25f) + (a > 0.75f) + (a > 1.25f) + (a > 1.75f)
            + (a > 2.5f)  + (a > 3.5f)  + (a > 5.0f);
    const unsigned long long lo = 0x3FC03F803F000000ull;  // bf16 bits {0,.5,1,1.5}
    const unsigned long long hi = 0x40C0408040404000ull;  // bf16 bits {2,3,4,6}
    unsigned long long tab = (idx < 4) ? lo : hi;
    unsigned short mag = (unsigned short)(tab >> ((idx & 3) * 16));
    unsigned short sgn = (unsigned short)((__float_as_uint(wv) >> 16) & 0x8000u);
    return (unsigned short)(mag | sgn);
}

__global__ void quant_kernel(const float4* __restrict__ w, size_t n4,
                             const unsigned int* __restrict__ amax,
                             ushort4* __restrict__ q) {
    const float scale = __uint_as_float(*amax) / 6.0f;
    size_t i = (size_t)blockIdx.x * blockDim.x + threadIdx.x;
    size_t stride = (size_t)gridDim.x * blockDim.x;
    for (; i < n4; i += stride) {
        float4 v = w[i];
        ushort4 o;
        o.x = quant_one(v.x, scale);
        o.y = quant_one(v.y, scale);
        o.z = quant_one(v.z, scale);
        o.w = quant_one(v.w, scale);
        q[i] = o;
    }
}

__global__ void cast_bf16_kernel(const float4* __restrict__ x, size_t n4,
                                 ushort4* __restrict__ o) {
    size_t i = (size_t)blockIdx.x * blockDim.x + threadIdx.x;
    size_t stride = (size_t)gridDim.x * blockDim.x;
    for (; i < n4; i += stride) {
        float4 v = x[i];
        ushort4 r;
        r.x = f2bf(v.x); r.y = f2bf(v.y); r.z = f2bf(v.z); r.w = f2bf(v.w);
        o[i] = r;
    }
}

// ===================== 256x256 8-phase GEMM (m201 template) =====================
// C[M][N] = A[M][K] (bf16) * B[N][K]^T (bf16), f32 acc.
// 512 thr = 8 waves (2M x 4N), per-wave 128x64 out, BK=64, 2 K-tiles/iter.
// LDS 128KiB: buf = tile parity; per buf: A0@0 A1@16K B0@32K B1@48K (16KiB halves).
// Half-tile layout: subtile s = (row/16)*2 + (k/32), 1024B each; within:
// byte = swz(row_in*64 + k_in*2), swz(x) = x ^ (((x>>9)&1)<<5)  [st_16x32].
// global_load_lds dest is LINEAR; source address carries the inverse swizzle.
// Stage stream runs 3 phases ahead: P1 stages (T+1).A1; P2..P5 stage T+2
// [B0,B1,A0,A1]; P6..P8 stage T+3 [B0,B1,A0]. Each half is overwritten exactly
// one phase after its last ds_read. vmcnt(6) at P4/P8 (counted, never 0 except
// final-iter P4) guarantees the next tile's halves have landed.

#define STG(gp, ldsoff)                                                         \
    do {                                                                        \
        __builtin_amdgcn_global_load_lds((const AS1 unsigned int*)((gp) + goff0), \
            (AS3 unsigned int*)(lds + (ldsoff) + tid * 16), 16, 0, 0);          \
        __builtin_amdgcn_global_load_lds((const AS1 unsigned int*)((gp) + goff1), \
            (AS3 unsigned int*)(lds + (ldsoff) + 8192 + tid * 16), 16, 0, 0);   \
    } while (0)

#define LDB(base)                                                   \
    do {                                                            \
        _Pragma("unroll") for (int j = 0; j < 4; ++j) {             \
            b_[j][0] = *(const short8*)((base) + (j * 2 + 0) * 1024); \
            b_[j][1] = *(const short8*)((base) + (j * 2 + 1) * 1024); \
        }                                                           \
    } while (0)

#define LDA(base, off)                                                        \
    do {                                                                      \
        _Pragma("unroll") for (int i = 0; i < 4; ++i) {                       \
            a_[i][0] = *(const short8*)((base) + (off) + (i * 2 + 0) * 1024); \
            a_[i][1] = *(const short8*)((base) + (off) + (i * 2 + 1) * 1024); \
        }                                                                     \
    } while (0)

#define MQ1(I, J)                                                              \
    do {                                                                       \
        acc[I][J] = __builtin_amdgcn_mfma_f32_16x16x32_bf16(a_[(I) & 3][0],    \
                        b_[J][0], acc[I][J], 0, 0, 0);                         \
        acc[I][J] = __builtin_amdgcn_mfma_f32_16x16x32_bf16(a_[(I) & 3][1],    \
                        b_[J][1], acc[I][J], 0, 0, 0);                         \
    } while (0)

#define MFMA_Q(I0, J0)                                              \
    do {                                                            \
        MQ1((I0) + 0, (J0) + 0); MQ1((I0) + 1, (J0) + 0);           \
        MQ1((I0) + 2, (J0) + 0); MQ1((I0) + 3, (J0) + 0);           \
        MQ1((I0) + 0, (J0) + 1); MQ1((I0) + 1, (J0) + 1);           \
        MQ1((I0) + 2, (J0) + 1); MQ1((I0) + 3, (J0) + 1);           \
    } while (0)

#define BAR() __builtin_amdgcn_s_barrier()
#define PRIO(x) __builtin_amdgcn_s_setprio(x)

template <int RELU_BF16>
__global__ __launch_bounds__(512, 2)
void gemm8(const unsigned short* __restrict__ A,
           const unsigned short* __restrict__ B,
           const float* __restrict__ bias,
           const unsigned int* __restrict__ amax,
           float* __restrict__ outF,
           unsigned short* __restrict__ outH,
           int M, int N, int K, int gx) {
    __shared__ __align__(16) char lds[131072];

    const int tid  = threadIdx.x;
    const int lane = tid & 63;
    const int wid  = tid >> 6;
    const int wm   = wid >> 2;   // 0..1: 128-row half
    const int wn   = wid & 3;    // 0..3: 64-col slice

    // XCD-aware swizzle (nwg % 8 == 0 for both our grids -> simple form is bijective)
    const int nwg = gridDim.x;
    const int wg  = blockIdx.x;
    const int swz = (wg & 7) * (nwg >> 3) + (wg >> 3);
    const int bx  = swz % gx;
    const int by  = swz / gx;
    const int col0 = bx * 256;
    const int row0 = by * 256;

    // per-lane swizzled ds_read byte offset within a 1024B subtile
    int sp = ((lane & 15) << 6) + ((lane >> 4) << 4);
    sp ^= ((sp >> 9) & 1) << 5;

    const char* ldsA_E = lds + wm * 16384 + sp;
    const char* ldsB_E = lds + 32768 + (wn >> 1) * 16384 + (wn & 1) * 8192 + sp;
    const char* ldsA_O = ldsA_E + 65536;
    const char* ldsB_O = ldsB_E + 65536;

    // stage source mapping: LDS linear offset o = l*8192 + tid*16 holds global
    // element (row,k) = unswz(o); precompute element offsets row*K + k.
    int goff0, goff1;
    {
        int o = tid * 16;
        int s = o >> 10, b = o & 1023;
        b ^= ((b >> 9) & 1) << 5;
        goff0 = (((s >> 1) << 4) + (b >> 6)) * K + ((s & 1) << 5) + ((b & 63) >> 1);
        o = 8192 + tid * 16;
        s = o >> 10; b = o & 1023;
        b ^= ((b >> 9) & 1) << 5;
        goff1 = (((s >> 1) << 4) + (b >> 6)) * K + ((s & 1) << 5) + ((b & 63) >> 1);
    }
    const unsigned short* pA0 = A + (size_t)row0 * K;
    const unsigned short* pA1 = A + (size_t)(row0 + 128) * K;
    const unsigned short* pB0 = B + (size_t)col0 * K;
    const unsigned short* pB1 = B + (size_t)(col0 + 128) * K;

    // ---- prologue: tile0 [B0,B1,A0,A1] -> buf0; tile1 [B0,B1,A0] -> buf1 ----
    STG(pB0, 32768); STG(pB1, 49152); STG(pA0, 0); STG(pA1, 16384);
    STG(pB0 + 64, 98304); STG(pB1 + 64, 114688); STG(pA0 + 64, 65536);
    asm volatile("s_waitcnt vmcnt(6)");   // tile0's 8 loads landed
    BAR();

    f32x4 acc[8][4] = {};
    short8 a_[4][2], b_[4][2];
    const int NIT = K >> 7;

    for (int it = 0; it < NIT; ++it) {
        const int o0 = it * 128;            // element k-offset of tile T=2*it
        const bool more = it < NIT - 1;

        // -------- P1: read bufE B-all + A-q0; stage (T+1).A1 -> bufO --------
        LDB(ldsB_E);
        LDA(ldsA_E, 0);
        STG(pA1 + o0 + 64, 81920);
        BAR();
        PRIO(1); MFMA_Q(0, 0); PRIO(0);
        BAR();
        // -------- P2: stage (T+2).B0 -> bufE --------
        if (more) STG(pB0 + o0 + 128, 32768);
        BAR();
        PRIO(1); MFMA_Q(0, 2); PRIO(0);
        BAR();
        // -------- P3: read bufE A-q1; stage (T+2).B1 --------
        LDA(ldsA_E, 8192);
        if (more) STG(pB1 + o0 + 128, 49152);
        BAR();
        PRIO(1); MFMA_Q(4, 2); PRIO(0);
        BAR();
        // -------- P4: stage (T+2).A0; counted vmcnt --------
        if (more) STG(pA0 + o0 + 128, 0);
        BAR();
        PRIO(1); MFMA_Q(4, 0); PRIO(0);
        if (more) { asm volatile("s_waitcnt vmcnt(6)"); }  // (T+1) fully landed
        else      { asm volatile("s_waitcnt vmcnt(0)"); }  // last iter: drain P1's stage
        BAR();
        // -------- P5: read bufO B-all + A-q0; stage (T+2).A1 --------
        LDB(ldsB_O);
        LDA(ldsA_O, 0);
        if (more) STG(pA1 + o0 + 128, 16384);
        BAR();
        PRIO(1); MFMA_Q(0, 0); PRIO(0);
        BAR();
        // -------- P6: stage (T+3).B0 -> bufO --------
        if (more) STG(pB0 + o0 + 192, 98304);
        BAR();
        PRIO(1); MFMA_Q(0, 2); PRIO(0);
        BAR();
        // -------- P7: read bufO A-q1; stage (T+3).B1 --------
        LDA(ldsA_O, 8192);
        if (more) STG(pB1 + o0 + 192, 114688);
        BAR();
        PRIO(1); MFMA_Q(4, 2); PRIO(0);
        BAR();
        // -------- P8: stage (T+3).A0; counted vmcnt --------
        if (more) STG(pA0 + o0 + 192, 65536);
        BAR();
        PRIO(1); MFMA_Q(4, 0); PRIO(0);
        asm volatile("s_waitcnt vmcnt(6)");  // (T+2) fully landed
        BAR();
    }

    // -------- epilogue: C/D layout col=lane&15, row=(lane>>4)*4+r --------
    const float scale = __uint_as_float(*amax) / 6.0f;
    #pragma unroll
    for (int j = 0; j < 4; ++j) {
        const int col = col0 + wn * 64 + j * 16 + (lane & 15);
        const float bvv = bias[col];
        #pragma unroll
        for (int i = 0; i < 8; ++i) {
            const int rbase = row0 + wm * 128 + i * 16 + (lane >> 4) * 4;
            #pragma unroll
            for (int r = 0; r < 4; ++r) {
                float v = acc[i][j][r] * scale + bvv;
                if (RELU_BF16) {
                    v = fmaxf(v, 0.0f);
                    outH[(size_t)(rbase + r) * N + col] = f2bf(v);
                } else {
                    outF[(size_t)(rbase + r) * N + col] = v;
                }
            }
        }
    }
}

extern "C" void kernel_launch(void* const* d_in, const int* in_sizes, int n_in,
                              void* d_out, int out_size, void* d_ws, size_t ws_size,
                              hipStream_t stream) {
    const float* x  = (const float*)d_in[0];   // [8192, 2048]
    const float* W1 = (const float*)d_in[1];   // [8192, 2048]
    const float* b1 = (const float*)d_in[2];   // [8192]
    const float* W2 = (const float*)d_in[3];   // [2048, 8192]
    const float* b2 = (const float*)d_in[4];   // [2048]
    float* out = (float*)d_out;                // [8192, 2048] f32

    const int Bm = 8192, Din = 2048, Dh = 8192, Dout = 2048;
    const size_t nW1 = (size_t)Dh * Din;
    const size_t nW2 = (size_t)Dout * Dh;
    const size_t nX  = (size_t)Bm * Din;
    const size_t nH  = (size_t)Bm * Dh;

    const size_t need = 256 + 2 * (nW1 + nW2 + nX + nH);
    if (ws_size < need) return;

    uint8_t* ws = (uint8_t*)d_ws;
    unsigned int*   amax = (unsigned int*)ws;
    unsigned short* Q1 = (unsigned short*)(ws + 256);
    unsigned short* Q2 = Q1 + nW1;
    unsigned short* Xb = Q2 + nW2;
    unsigned short* H  = Xb + nX;

    init_amax<<<1, 64, 0, stream>>>(amax);
    absmax_kernel<<<1024, 256, 0, stream>>>((const float4*)W1, nW1 / 4, amax + 0);
    absmax_kernel<<<1024, 256, 0, stream>>>((const float4*)W2, nW2 / 4, amax + 1);
    quant_kernel<<<2048, 256, 0, stream>>>((const float4*)W1, nW1 / 4, amax + 0, (ushort4*)Q1);
    quant_kernel<<<2048, 256, 0, stream>>>((const float4*)W2, nW2 / 4, amax + 1, (ushort4*)Q2);
    cast_bf16_kernel<<<2048, 256, 0, stream>>>((const float4*)x, nX / 4, (ushort4*)Xb);

    // h = relu(scale1 * (x @ Q1^T) + b1) -> bf16
    gemm8<1><<<dim3((Dh / 256) * (Bm / 256)), 512, 0, stream>>>(
        Xb, Q1, b1, amax + 0, nullptr, H, Bm, Dh, Din, Dh / 256);
    // y = scale2 * (h @ Q2^T) + b2 -> f32
    gemm8<0><<<dim3((Dout / 256) * (Bm / 256)), 512, 0, stream>>>(
        H, Q2, b2, amax + 1, out, nullptr, Bm, Dout, Dh, Dout / 256);
}